// Round 1
// baseline (135.876 us; speedup 1.0000x reference)
//
#include <hip/hip_runtime.h>
#include <hip/hip_bf16.h>

#define NH   32
#define NKVH 8
#define NG   4
#define DD   128
#define HID  4096
#define NQKV 6144
#define NB   32
#define SS   2048
#define SCALE 0.08838834764831845f
#define CHUNK 256
#define NCHUNK 8

typedef __attribute__((ext_vector_type(4))) float f32x4;
typedef __attribute__((ext_vector_type(8))) short bf16x8;

static __device__ __forceinline__ unsigned short f2bf(float f) {
    __hip_bfloat16 h = __float2bfloat16(f);
    return __builtin_bit_cast(unsigned short, h);
}

// ---------------- convert hidden_states to bf16 ----------------
__global__ void cvt_hs(const float* __restrict__ in, unsigned short* __restrict__ out) {
    int i = blockIdx.x * 256 + threadIdx.x;   // 131072 total
    out[i] = f2bf(in[i]);
}

// ---------------- skinny GEMM: Out[32][N] = Abf[32][K] * W[N][K]^T ----------------
// grid.x = N/16 ; block = 256 (4 waves). Wave w handles K-range [w*K/4,(w+1)*K/4),
// LDS-reduce at the end.
__global__ __launch_bounds__(256) void gemm32(
    const unsigned short* __restrict__ Abf,
    const float* __restrict__ W,
    float* __restrict__ Out,
    int K, int N) {
    int j0 = blockIdx.x * 16;
    int tid = threadIdx.x;
    int wave = tid >> 6;
    int lane = tid & 63;
    int l16 = lane & 15;
    int kgrp = lane >> 4;
    int Kq = K >> 2;
    int kbeg = wave * Kq, kend = kbeg + Kq;

    f32x4 acc0 = {0.f, 0.f, 0.f, 0.f};
    f32x4 acc1 = {0.f, 0.f, 0.f, 0.f};
    const unsigned short* arow0 = Abf + (size_t)l16 * K;
    const unsigned short* arow1 = Abf + (size_t)(16 + l16) * K;
    const float* wrow = W + (size_t)(j0 + l16) * K;

#pragma unroll 2
    for (int k = kbeg; k < kend; k += 32) {
        int kk = k + kgrp * 8;
        bf16x8 a0 = *(const bf16x8*)(arow0 + kk);
        bf16x8 a1 = *(const bf16x8*)(arow1 + kk);
        f32x4 w0 = *(const f32x4*)(wrow + kk);
        f32x4 w1 = *(const f32x4*)(wrow + kk + 4);
        bf16x8 bw;
        bw[0] = (short)f2bf(w0[0]); bw[1] = (short)f2bf(w0[1]);
        bw[2] = (short)f2bf(w0[2]); bw[3] = (short)f2bf(w0[3]);
        bw[4] = (short)f2bf(w1[0]); bw[5] = (short)f2bf(w1[1]);
        bw[6] = (short)f2bf(w1[2]); bw[7] = (short)f2bf(w1[3]);
        acc0 = __builtin_amdgcn_mfma_f32_16x16x32_bf16(a0, bw, acc0, 0, 0, 0);
        acc1 = __builtin_amdgcn_mfma_f32_16x16x32_bf16(a1, bw, acc1, 0, 0, 0);
    }

    __shared__ f32x4 red[4][2][64];
    red[wave][0][lane] = acc0;
    red[wave][1][lane] = acc1;
    __syncthreads();
    if (wave == 0) {
        for (int t = 0; t < 2; ++t) {
            f32x4 s = red[0][t][lane];
            s += red[1][t][lane];
            s += red[2][t][lane];
            s += red[3][t][lane];
            for (int r = 0; r < 4; ++r)
                Out[(size_t)(t * 16 + kgrp * 4 + r) * N + j0 + l16] = s[r];
        }
    }
}

// ---------------- RoPE ----------------
// thread per (b, head(0..39), i<64). heads 0..31 = q, 32..39 = k.
__global__ void rope_kernel(const float* __restrict__ qkv, const int* __restrict__ positions,
                            float* __restrict__ q_rope, float* __restrict__ k_rope) {
    int idx = blockIdx.x * 256 + threadIdx.x;   // 32*40*64 = 81920
    if (idx >= NB * 40 * 64) return;
    int i = idx & 63;
    int head = (idx >> 6) % 40;
    int b = idx / (64 * 40);
    float pos = (float)positions[b];
    // inv_freq = theta^(-i/64) = exp2(-i * log2(theta)/64)
    float inv = exp2f(-(float)i * 0.20762050593046f);
    float f = pos * inv;
    float s, c;
    sincosf(f, &s, &c);
    const float* src = qkv + (size_t)b * NQKV + head * DD;
    float x1 = src[i], x2 = src[i + 64];
    float o1 = x1 * c - x2 * s;
    float o2 = x2 * c + x1 * s;
    if (head < NH) {
        float* dst = q_rope + ((size_t)b * NH + head) * DD;
        dst[i] = o1; dst[i + 64] = o2;
    } else {
        float* dst = k_rope + ((size_t)b * NKVH + (head - NH)) * DD;
        dst[i] = o1; dst[i + 64] = o2;
    }
}

// ---------------- attention partial (flash-decode, split-S) ----------------
// grid: (B*KVH, NCHUNK), block 256. part stride per (bk,c): 520 f32 = {m[4], l[4], acc[4][128]}
__global__ __launch_bounds__(256) void attn_partial(
    const float* __restrict__ k_cache, const float* __restrict__ v_cache,
    const float* __restrict__ q_rope, const float* __restrict__ k_rope,
    const float* __restrict__ qkv, const int* __restrict__ positions,
    float* __restrict__ part) {
    int bk = blockIdx.x;
    int c = blockIdx.y;
    int b = bk >> 3, kvh = bk & 7;
    int pos = positions[b];
    int s0 = c * CHUNK;
    float* mypart = part + ((size_t)bk * NCHUNK + c) * 520;
    int tid = threadIdx.x;
    if (s0 > pos) {
        if (tid < 4) { mypart[tid] = -__builtin_inff(); mypart[4 + tid] = 0.f; }
        return;
    }
    int nvalid = min(pos + 1 - s0, CHUNK);

    __shared__ float sc[4][CHUNK];
    __shared__ float mg[4], lg[4];
    __shared__ f32x4 red[8][4][32];

    for (int i = tid; i < 4 * CHUNK; i += 256) ((float*)sc)[i] = -__builtin_inff();
    __syncthreads();

    int wave = tid >> 6, lane = tid & 63, l16 = lane & 15, rsub = lane >> 4;

    // q fragments: qf[g][e], d = l16*8+e
    float qf[4][8];
    const float* qbase = q_rope + ((size_t)b * NH + kvh * NG) * DD;
#pragma unroll
    for (int g = 0; g < 4; ++g)
#pragma unroll
        for (int e = 0; e < 8; ++e)
            qf[g][e] = qbase[g * DD + l16 * 8 + e];

    // scores
    for (int it = 0; it < CHUNK / 16; ++it) {
        int row = it * 16 + wave * 4 + rsub;
        if (row >= nvalid) continue;   // uniform over each 16-lane group
        int s = s0 + row;
        const float* krow = (s == pos)
            ? (k_rope + ((size_t)b * NKVH + kvh) * DD)
            : (k_cache + (((size_t)b * SS + s) * NKVH + kvh) * DD);
        f32x4 k0 = *(const f32x4*)(krow + l16 * 8);
        f32x4 k1 = *(const f32x4*)(krow + l16 * 8 + 4);
        float dots[4];
#pragma unroll
        for (int g = 0; g < 4; ++g) {
            dots[g] = qf[g][0] * k0[0] + qf[g][1] * k0[1] + qf[g][2] * k0[2] + qf[g][3] * k0[3]
                    + qf[g][4] * k1[0] + qf[g][5] * k1[1] + qf[g][6] * k1[2] + qf[g][7] * k1[3];
        }
#pragma unroll
        for (int m = 1; m < 16; m <<= 1)
#pragma unroll
            for (int g = 0; g < 4; ++g)
                dots[g] += __shfl_xor(dots[g], m, 64);
        if (l16 == 0)
#pragma unroll
            for (int g = 0; g < 4; ++g) sc[g][row] = dots[g] * SCALE;
    }
    __syncthreads();

    // softmax partial: wave g handles row-group g
    {
        int g = wave;
        float v0 = sc[g][lane], v1 = sc[g][lane + 64], v2 = sc[g][lane + 128], v3 = sc[g][lane + 192];
        float m = fmaxf(fmaxf(v0, v1), fmaxf(v2, v3));
#pragma unroll
        for (int msk = 1; msk < 64; msk <<= 1) m = fmaxf(m, __shfl_xor(m, msk, 64));
        float p0 = expf(v0 - m), p1 = expf(v1 - m), p2 = expf(v2 - m), p3 = expf(v3 - m);
        float l = p0 + p1 + p2 + p3;
#pragma unroll
        for (int msk = 1; msk < 64; msk <<= 1) l += __shfl_xor(l, msk, 64);
        sc[g][lane] = p0; sc[g][lane + 64] = p1; sc[g][lane + 128] = p2; sc[g][lane + 192] = p3;
        if (lane == 0) { mg[g] = m; lg[g] = l; }
    }
    __syncthreads();

    // PV: thread (sid = tid>>5 s-split, l32 = tid&31 d-chunk), 4 g's per thread
    int sid = tid >> 5, l32 = tid & 31;
    f32x4 acc[4] = {{0.f,0.f,0.f,0.f},{0.f,0.f,0.f,0.f},{0.f,0.f,0.f,0.f},{0.f,0.f,0.f,0.f}};
    for (int row = sid; row < nvalid; row += 8) {
        int s = s0 + row;
        const float* vrow = (s == pos)
            ? (qkv + (size_t)b * NQKV + (NH + NKVH) * DD + kvh * DD)
            : (v_cache + (((size_t)b * SS + s) * NKVH + kvh) * DD);
        f32x4 v4 = *(const f32x4*)(vrow + l32 * 4);
#pragma unroll
        for (int g = 0; g < 4; ++g)
            acc[g] += sc[g][row] * v4;
    }
#pragma unroll
    for (int g = 0; g < 4; ++g) red[sid][g][l32] = acc[g];
    __syncthreads();

    if (tid < 128) {
        int g = tid >> 5, l = tid & 31;
        f32x4 s = red[0][g][l];
#pragma unroll
        for (int w = 1; w < 8; ++w) s += red[w][g][l];
        *(f32x4*)(mypart + 8 + g * DD + l * 4) = s;
        if (l == 0) { mypart[g] = mg[g]; mypart[4 + g] = lg[g]; }
    }
}

// ---------------- combine partials -> attn activations (bf16) ----------------
__global__ __launch_bounds__(128) void attn_combine(
    const float* __restrict__ part, unsigned short* __restrict__ attn_bf) {
    int bk = blockIdx.x;
    int b = bk >> 3, kvh = bk & 7;
    const float* p0 = part + (size_t)bk * NCHUNK * 520;
    int tid = threadIdx.x;
    int g = tid >> 5, l32 = tid & 31;

    float M = -__builtin_inff();
#pragma unroll
    for (int c = 0; c < NCHUNK; ++c) {
        float lcv = p0[c * 520 + 4 + g];
        float mcv = p0[c * 520 + g];
        if (lcv > 0.f && mcv > M) M = mcv;
    }
    float L = 0.f;
    f32x4 acc = {0.f, 0.f, 0.f, 0.f};
#pragma unroll
    for (int c = 0; c < NCHUNK; ++c) {
        float lcv = p0[c * 520 + 4 + g];
        float mcv = p0[c * 520 + g];
        if (lcv > 0.f) {
            float wgt = expf(mcv - M);
            L += lcv * wgt;
            f32x4 a = *(const f32x4*)(p0 + c * 520 + 8 + g * DD + l32 * 4);
            acc += wgt * a;
        }
    }
    float inv = 1.0f / L;
    unsigned short* o = attn_bf + (((size_t)b * NH) + kvh * NG + g) * DD + l32 * 4;
#pragma unroll
    for (int r = 0; r < 4; ++r) o[r] = f2bf(acc[r] * inv);
}

extern "C" void kernel_launch(void* const* d_in, const int* in_sizes, int n_in,
                              void* d_out, int out_size, void* d_ws, size_t ws_size,
                              hipStream_t stream) {
    const float* hs      = (const float*)d_in[0];
    const float* w_qkv   = (const float*)d_in[1];
    const float* w_o     = (const float*)d_in[2];
    const float* k_cache = (const float*)d_in[3];
    const float* v_cache = (const float*)d_in[4];
    const int*   positions = (const int*)d_in[5];
    float* out = (float*)d_out;

    char* ws = (char*)d_ws;
    unsigned short* hs_bf  = (unsigned short*)(ws);             // 262144 B
    float* qkv             = (float*)(ws + 262144);             // 786432 B
    float* q_rope          = (float*)(ws + 1048576);            // 524288 B
    float* k_rope          = (float*)(ws + 1572864);            // 131072 B
    float* part            = (float*)(ws + 1703936);            // 4259840 B
    unsigned short* attn_bf = (unsigned short*)(ws + 5963776);  // 262144 B

    hipLaunchKernelGGL(cvt_hs, dim3(512), dim3(256), 0, stream, hs, hs_bf);
    hipLaunchKernelGGL(gemm32, dim3(NQKV / 16), dim3(256), 0, stream, hs_bf, w_qkv, qkv, HID, NQKV);
    hipLaunchKernelGGL(rope_kernel, dim3(320), dim3(256), 0, stream, qkv, positions, q_rope, k_rope);
    hipLaunchKernelGGL(attn_partial, dim3(NB * NKVH, NCHUNK), dim3(256), 0, stream,
                       k_cache, v_cache, q_rope, k_rope, qkv, positions, part);
    hipLaunchKernelGGL(attn_combine, dim3(NB * NKVH), dim3(128), 0, stream, part, attn_bf);
    hipLaunchKernelGGL(gemm32, dim3(HID / 16), dim3(256), 0, stream, attn_bf, w_o, out, HID, HID);
}

// Round 2
// 130.946 us; speedup vs baseline: 1.0376x; 1.0376x over previous
//
#include <hip/hip_runtime.h>
#include <hip/hip_bf16.h>

#define NH   32
#define NKVH 8
#define NG   4
#define DD   128
#define HID  4096
#define NQKV 6144
#define NB   32
#define SS   2048
#define SCALE 0.08838834764831845f
#define CHUNK 128
#define NCHUNK 16

typedef __attribute__((ext_vector_type(4))) float f32x4;
typedef __attribute__((ext_vector_type(8))) short bf16x8;

static __device__ __forceinline__ unsigned short f2bf(float f) {
    __hip_bfloat16 h = __float2bfloat16(f);
    return __builtin_bit_cast(unsigned short, h);
}

// ---------------- convert hidden_states to bf16 ----------------
__global__ void cvt_hs(const float* __restrict__ in, unsigned short* __restrict__ out) {
    int i = blockIdx.x * 256 + threadIdx.x;   // 131072 total
    out[i] = f2bf(in[i]);
}

// ---------------- skinny GEMM with grid split-K ----------------
// Part[ks][32][N] += Abf[32][Kslice] * W[N][Kslice]^T for K-slice ks.
// grid = (N/16, SPLIT); block = 256 (4 waves), wave splits slice /4.
template<int SPLIT>
__global__ __launch_bounds__(256) void gemm32_s(
    const unsigned short* __restrict__ Abf,
    const float* __restrict__ W,
    float* __restrict__ Part,
    int K, int N) {
    int j0 = blockIdx.x * 16;
    int ks = blockIdx.y;
    int tid = threadIdx.x;
    int wave = tid >> 6;
    int lane = tid & 63;
    int l16 = lane & 15;
    int kgrp = lane >> 4;
    int Kslice = K / SPLIT;
    int Kq = Kslice >> 2;
    int kbeg = ks * Kslice + wave * Kq;
    int kend = kbeg + Kq;

    f32x4 acc0 = {0.f, 0.f, 0.f, 0.f};
    f32x4 acc1 = {0.f, 0.f, 0.f, 0.f};
    const unsigned short* arow0 = Abf + (size_t)l16 * K;
    const unsigned short* arow1 = Abf + (size_t)(16 + l16) * K;
    const float* wrow = W + (size_t)(j0 + l16) * K;

#pragma unroll 2
    for (int k = kbeg; k < kend; k += 32) {
        int kk = k + kgrp * 8;
        bf16x8 a0 = *(const bf16x8*)(arow0 + kk);
        bf16x8 a1 = *(const bf16x8*)(arow1 + kk);
        f32x4 w0 = *(const f32x4*)(wrow + kk);
        f32x4 w1 = *(const f32x4*)(wrow + kk + 4);
        bf16x8 bw;
        bw[0] = (short)f2bf(w0[0]); bw[1] = (short)f2bf(w0[1]);
        bw[2] = (short)f2bf(w0[2]); bw[3] = (short)f2bf(w0[3]);
        bw[4] = (short)f2bf(w1[0]); bw[5] = (short)f2bf(w1[1]);
        bw[6] = (short)f2bf(w1[2]); bw[7] = (short)f2bf(w1[3]);
        acc0 = __builtin_amdgcn_mfma_f32_16x16x32_bf16(a0, bw, acc0, 0, 0, 0);
        acc1 = __builtin_amdgcn_mfma_f32_16x16x32_bf16(a1, bw, acc1, 0, 0, 0);
    }

    __shared__ f32x4 red[4][2][64];
    red[wave][0][lane] = acc0;
    red[wave][1][lane] = acc1;
    __syncthreads();
    if (wave == 0) {
        for (int t = 0; t < 2; ++t) {
            f32x4 s = red[0][t][lane];
            s += red[1][t][lane];
            s += red[2][t][lane];
            s += red[3][t][lane];
            for (int r = 0; r < 4; ++r)
                Part[((size_t)ks * 32 + t * 16 + kgrp * 4 + r) * N + j0 + l16] = s[r];
        }
    }
}

// ---------------- reduce qkv partials + RoPE + v extract ----------------
// part: [2][32][NQKV]. threads: [0,81920) rope pairs (b, head<40, i<64);
// [81920, 114688) v elems (b, kvh, d).
__global__ __launch_bounds__(256) void reduce_rope(
    const float* __restrict__ part, const int* __restrict__ positions,
    float* __restrict__ q_rope, float* __restrict__ k_rope, float* __restrict__ vbuf) {
    int idx = blockIdx.x * 256 + threadIdx.x;
    const int NROPE = NB * 40 * 64;
    const int NV = NB * NKVH * DD;
    if (idx < NROPE) {
        int i = idx & 63;
        int head = (idx >> 6) % 40;
        int b = idx / (64 * 40);
        size_t base = (size_t)b * NQKV + head * DD;
        float x1 = part[base + i] + part[(size_t)32 * NQKV + base + i];
        float x2 = part[base + i + 64] + part[(size_t)32 * NQKV + base + i + 64];
        float pos = (float)positions[b];
        float inv = exp2f(-(float)i * 0.20762050593046f);   // theta^(-i/64)
        float f = pos * inv;
        float s, c;
        sincosf(f, &s, &c);
        float o1 = x1 * c - x2 * s;
        float o2 = x2 * c + x1 * s;
        if (head < NH) {
            float* dst = q_rope + ((size_t)b * NH + head) * DD;
            dst[i] = o1; dst[i + 64] = o2;
        } else {
            float* dst = k_rope + ((size_t)b * NKVH + (head - NH)) * DD;
            dst[i] = o1; dst[i + 64] = o2;
        }
    } else if (idx < NROPE + NV) {
        int j = idx - NROPE;
        size_t base = (size_t)(j >> 10) * NQKV + (NH + NKVH) * DD + (j & 1023);
        vbuf[j] = part[base] + part[(size_t)32 * NQKV + base];
    }
}

// ---------------- attention partial (flash-decode, split-S) ----------------
// grid: (B*KVH, NCHUNK), block 256. part stride per (bk,c): 520 f32 = {m[4], l[4], acc[4][128]}
__global__ __launch_bounds__(256) void attn_partial(
    const float* __restrict__ k_cache, const float* __restrict__ v_cache,
    const float* __restrict__ q_rope, const float* __restrict__ k_rope,
    const float* __restrict__ vbuf, const int* __restrict__ positions,
    float* __restrict__ part) {
    int bk = blockIdx.x;
    int c = blockIdx.y;
    int b = bk >> 3, kvh = bk & 7;
    int pos = positions[b];
    int s0 = c * CHUNK;
    float* mypart = part + ((size_t)bk * NCHUNK + c) * 520;
    int tid = threadIdx.x;
    if (s0 > pos) {
        if (tid < 4) { mypart[tid] = -__builtin_inff(); mypart[4 + tid] = 0.f; }
        return;
    }
    int nvalid = min(pos + 1 - s0, CHUNK);

    __shared__ float sc[4][CHUNK];
    __shared__ float mg[4], lg[4];
    __shared__ f32x4 red[8][4][32];

    for (int i = tid; i < 4 * CHUNK; i += 256) ((float*)sc)[i] = -__builtin_inff();
    __syncthreads();

    int wave = tid >> 6, lane = tid & 63, l16 = lane & 15, rsub = lane >> 4;

    // q fragments: qf[g][e], d = l16*8+e
    float qf[4][8];
    const float* qbase = q_rope + ((size_t)b * NH + kvh * NG) * DD;
#pragma unroll
    for (int g = 0; g < 4; ++g)
#pragma unroll
        for (int e = 0; e < 8; ++e)
            qf[g][e] = qbase[g * DD + l16 * 8 + e];

    // scores
    for (int it = 0; it < CHUNK / 16; ++it) {
        int row = it * 16 + wave * 4 + rsub;
        if (row >= nvalid) continue;
        int s = s0 + row;
        const float* krow = (s == pos)
            ? (k_rope + ((size_t)b * NKVH + kvh) * DD)
            : (k_cache + (((size_t)b * SS + s) * NKVH + kvh) * DD);
        f32x4 k0 = *(const f32x4*)(krow + l16 * 8);
        f32x4 k1 = *(const f32x4*)(krow + l16 * 8 + 4);
        float dots[4];
#pragma unroll
        for (int g = 0; g < 4; ++g) {
            dots[g] = qf[g][0] * k0[0] + qf[g][1] * k0[1] + qf[g][2] * k0[2] + qf[g][3] * k0[3]
                    + qf[g][4] * k1[0] + qf[g][5] * k1[1] + qf[g][6] * k1[2] + qf[g][7] * k1[3];
        }
#pragma unroll
        for (int m = 1; m < 16; m <<= 1)
#pragma unroll
            for (int g = 0; g < 4; ++g)
                dots[g] += __shfl_xor(dots[g], m, 64);
        if (l16 == 0)
#pragma unroll
            for (int g = 0; g < 4; ++g) sc[g][row] = dots[g] * SCALE;
    }
    __syncthreads();

    // softmax partial: wave g handles row-group g (CHUNK=128 -> 2 vals/lane)
    {
        int g = wave;
        float v0 = sc[g][lane], v1 = sc[g][lane + 64];
        float m = fmaxf(v0, v1);
#pragma unroll
        for (int msk = 1; msk < 64; msk <<= 1) m = fmaxf(m, __shfl_xor(m, msk, 64));
        float p0 = expf(v0 - m), p1 = expf(v1 - m);
        float l = p0 + p1;
#pragma unroll
        for (int msk = 1; msk < 64; msk <<= 1) l += __shfl_xor(l, msk, 64);
        sc[g][lane] = p0; sc[g][lane + 64] = p1;
        if (lane == 0) { mg[g] = m; lg[g] = l; }
    }
    __syncthreads();

    // PV: thread (sid = tid>>5 s-split, l32 = tid&31 d-chunk), 4 g's per thread
    int sid = tid >> 5, l32 = tid & 31;
    f32x4 acc[4] = {{0.f,0.f,0.f,0.f},{0.f,0.f,0.f,0.f},{0.f,0.f,0.f,0.f},{0.f,0.f,0.f,0.f}};
    for (int row = sid; row < nvalid; row += 8) {
        int s = s0 + row;
        const float* vrow = (s == pos)
            ? (vbuf + ((size_t)b * NKVH + kvh) * DD)
            : (v_cache + (((size_t)b * SS + s) * NKVH + kvh) * DD);
        f32x4 v4 = *(const f32x4*)(vrow + l32 * 4);
#pragma unroll
        for (int g = 0; g < 4; ++g)
            acc[g] += sc[g][row] * v4;
    }
#pragma unroll
    for (int g = 0; g < 4; ++g) red[sid][g][l32] = acc[g];
    __syncthreads();

    if (tid < 128) {
        int g = tid >> 5, l = tid & 31;
        f32x4 s = red[0][g][l];
#pragma unroll
        for (int w = 1; w < 8; ++w) s += red[w][g][l];
        *(f32x4*)(mypart + 8 + g * DD + l * 4) = s;
        if (l == 0) { mypart[g] = mg[g]; mypart[4 + g] = lg[g]; }
    }
}

// ---------------- combine partials -> attn activations (bf16) ----------------
__global__ __launch_bounds__(128) void attn_combine(
    const float* __restrict__ part, unsigned short* __restrict__ attn_bf) {
    int bk = blockIdx.x;
    int b = bk >> 3, kvh = bk & 7;
    const float* p0 = part + (size_t)bk * NCHUNK * 520;
    int tid = threadIdx.x;
    int g = tid >> 5, l32 = tid & 31;

    float M = -__builtin_inff();
#pragma unroll
    for (int c = 0; c < NCHUNK; ++c) {
        float lcv = p0[c * 520 + 4 + g];
        float mcv = p0[c * 520 + g];
        if (lcv > 0.f && mcv > M) M = mcv;
    }
    float L = 0.f;
    f32x4 acc = {0.f, 0.f, 0.f, 0.f};
#pragma unroll
    for (int c = 0; c < NCHUNK; ++c) {
        float lcv = p0[c * 520 + 4 + g];
        float mcv = p0[c * 520 + g];
        if (lcv > 0.f) {
            float wgt = expf(mcv - M);
            L += lcv * wgt;
            f32x4 a = *(const f32x4*)(p0 + c * 520 + 8 + g * DD + l32 * 4);
            acc += wgt * a;
        }
    }
    float inv = 1.0f / L;
    unsigned short* o = attn_bf + (((size_t)b * NH) + kvh * NG + g) * DD + l32 * 4;
#pragma unroll
    for (int r = 0; r < 4; ++r) o[r] = f2bf(acc[r] * inv);
}

// ---------------- reduce o partials -> out ----------------
__global__ __launch_bounds__(256) void reduce_o(const float* __restrict__ part,
                                                float* __restrict__ out) {
    int idx = blockIdx.x * 256 + threadIdx.x;   // 32768 f32x4 groups
    const f32x4* p = (const f32x4*)part;
    f32x4 s = p[idx];
    s += p[idx + 32768];
    s += p[idx + 65536];
    s += p[idx + 98304];
    ((f32x4*)out)[idx] = s;
}

extern "C" void kernel_launch(void* const* d_in, const int* in_sizes, int n_in,
                              void* d_out, int out_size, void* d_ws, size_t ws_size,
                              hipStream_t stream) {
    const float* hs      = (const float*)d_in[0];
    const float* w_qkv   = (const float*)d_in[1];
    const float* w_o     = (const float*)d_in[2];
    const float* k_cache = (const float*)d_in[3];
    const float* v_cache = (const float*)d_in[4];
    const int*   positions = (const int*)d_in[5];
    float* out = (float*)d_out;

    char* ws = (char*)d_ws;
    unsigned short* hs_bf   = (unsigned short*)(ws);             // 262144 B
    float* qkv_part         = (float*)(ws + 262144);             // 1572864 B
    float* q_rope           = (float*)(ws + 1835008);            // 524288 B
    float* k_rope           = (float*)(ws + 2359296);            // 131072 B
    float* vbuf             = (float*)(ws + 2490368);            // 131072 B
    float* part             = (float*)(ws + 2621440);            // 8519680 B
    unsigned short* attn_bf = (unsigned short*)(ws + 11141120);  // 262144 B
    float* o_part           = (float*)(ws + 11403264);           // 2097152 B

    hipLaunchKernelGGL(cvt_hs, dim3(512), dim3(256), 0, stream, hs, hs_bf);
    hipLaunchKernelGGL((gemm32_s<2>), dim3(NQKV / 16, 2), dim3(256), 0, stream,
                       hs_bf, w_qkv, qkv_part, HID, NQKV);
    hipLaunchKernelGGL(reduce_rope, dim3(448), dim3(256), 0, stream,
                       qkv_part, positions, q_rope, k_rope, vbuf);
    hipLaunchKernelGGL(attn_partial, dim3(NB * NKVH, NCHUNK), dim3(256), 0, stream,
                       k_cache, v_cache, q_rope, k_rope, vbuf, positions, part);
    hipLaunchKernelGGL(attn_combine, dim3(NB * NKVH), dim3(128), 0, stream, part, attn_bf);
    hipLaunchKernelGGL((gemm32_s<4>), dim3(HID / 16, 4), dim3(256), 0, stream,
                       attn_bf, w_o, o_part, HID, HID);
    hipLaunchKernelGGL(reduce_o, dim3(128), dim3(256), 0, stream, o_part, out);
}